// Round 1
// baseline (284.578 us; speedup 1.0000x reference)
//
#include <hip/hip_runtime.h>
#include <hip/hip_bf16.h>

#define D 64
#define LANES_PER_ROW 16   // 16 lanes x float4 = 64 dims

// Kernel 1: playlist_h[p][:] = 0.5*(track_emb[s0][:] + track_emb[s1][:])
__global__ void __launch_bounds__(256) playlist_mean_kernel(
    const float* __restrict__ track_emb,
    const int* __restrict__ sampled,   // [P,2]
    float* __restrict__ ph,            // [P,D]
    int P) {
  int tid = blockIdx.x * blockDim.x + threadIdx.x;
  int p = tid >> 4;          // playlist
  int l = tid & 15;          // float4 slot within row
  if (p >= P) return;
  int s0 = sampled[2 * p + 0];
  int s1 = sampled[2 * p + 1];
  const float4 a = *(const float4*)(track_emb + (size_t)s0 * D + l * 4);
  const float4 b = *(const float4*)(track_emb + (size_t)s1 * D + l * 4);
  float4 r;
  r.x = 0.5f * (a.x + b.x);
  r.y = 0.5f * (a.y + b.y);
  r.z = 0.5f * (a.z + b.z);
  r.w = 0.5f * (a.w + b.w);
  *(float4*)(ph + (size_t)p * D + l * 4) = r;
}

// Kernel 2: out[e] = dot(ph[edge_src[e]], track_emb[edge_dst[e]])
__global__ void __launch_bounds__(256) edge_score_kernel(
    const float* __restrict__ ph,
    const float* __restrict__ track_emb,
    const int* __restrict__ esrc,
    const int* __restrict__ edst,
    float* __restrict__ out,
    int E) {
  int tid = blockIdx.x * blockDim.x + threadIdx.x;
  int e = tid >> 4;          // edge
  int l = tid & 15;          // float4 slot
  if (e >= E) return;
  int s = esrc[e];           // broadcast within 16-lane group (same addr)
  int d = edst[e];
  const float4 a = *(const float4*)(ph + (size_t)s * D + l * 4);
  const float4 b = *(const float4*)(track_emb + (size_t)d * D + l * 4);
  float v = a.x * b.x + a.y * b.y + a.z * b.z + a.w * b.w;
  // reduce across the 16 lanes of this row group (xor stays within group)
  v += __shfl_xor(v, 1, 64);
  v += __shfl_xor(v, 2, 64);
  v += __shfl_xor(v, 4, 64);
  v += __shfl_xor(v, 8, 64);
  if (l == 0) out[e] = v;
}

extern "C" void kernel_launch(void* const* d_in, const int* in_sizes, int n_in,
                              void* d_out, int out_size, void* d_ws, size_t ws_size,
                              hipStream_t stream) {
  const float* track_emb = (const float*)d_in[0];   // [N_TRACKS, 64] f32
  const int*   edge_src  = (const int*)d_in[1];     // [E]
  const int*   edge_dst  = (const int*)d_in[2];     // [E]
  const int*   sampled   = (const int*)d_in[3];     // [P, 2]
  float* out = (float*)d_out;                       // [E] f32

  const int E = in_sizes[1];
  const int P = in_sizes[3] / 2;

  float* ph = (float*)d_ws;                         // [P, 64] f32 = 25.6 MB

  // Kernel 1: P*16 threads
  {
    long long t = (long long)P * LANES_PER_ROW;
    int blocks = (int)((t + 255) / 256);
    playlist_mean_kernel<<<blocks, 256, 0, stream>>>(track_emb, sampled, ph, P);
  }
  // Kernel 2: E*16 threads
  {
    long long t = (long long)E * LANES_PER_ROW;
    int blocks = (int)((t + 255) / 256);
    edge_score_kernel<<<blocks, 256, 0, stream>>>(ph, track_emb, edge_src, edge_dst, out, E);
  }
}

// Round 2
// 175.774 us; speedup vs baseline: 1.6190x; 1.6190x over previous
//
#include <hip/hip_runtime.h>
#include <hip/hip_bf16.h>

#define D 64

typedef unsigned int   u32;
typedef unsigned short u16;

__device__ __forceinline__ u16 f32_to_bf16_rn(float f) {
  u32 u = __float_as_uint(f);
  u32 r = (u + 0x7FFFu + ((u >> 16) & 1u)) >> 16;   // round-to-nearest-even
  return (u16)r;
}

// ---------------- bf16 path ----------------

// Kernel A: streaming f32 -> bf16 conversion of track_emb.
// Unit of work: 4 floats -> 4 bf16 (uint2 write).
__global__ void __launch_bounds__(256) conv_bf16_kernel(
    const float4* __restrict__ in, uint2* __restrict__ out, long n4) {
  long stride = (long)gridDim.x * blockDim.x;
  for (long i = (long)blockIdx.x * blockDim.x + threadIdx.x; i < n4; i += stride) {
    float4 v = in[i];
    uint2 o;
    o.x = (u32)f32_to_bf16_rn(v.x) | ((u32)f32_to_bf16_rn(v.y) << 16);
    o.y = (u32)f32_to_bf16_rn(v.z) | ((u32)f32_to_bf16_rn(v.w) << 16);
    out[i] = o;
  }
}

// Kernel B: ph[p][:] = bf16(0.5*(emb[s0][:] + emb[s1][:]))  (reads f32 emb)
__global__ void __launch_bounds__(256) ph_build_bf16_kernel(
    const float* __restrict__ track_emb,
    const int* __restrict__ sampled,   // [P,2]
    u16* __restrict__ ph,              // [P,D] bf16
    int P) {
  int tid = blockIdx.x * blockDim.x + threadIdx.x;
  int p = tid >> 4;
  int l = tid & 15;                    // 16 lanes x 4 floats
  if (p >= P) return;
  int s0 = sampled[2 * p + 0];
  int s1 = sampled[2 * p + 1];
  const float4 a = *(const float4*)(track_emb + (size_t)s0 * D + l * 4);
  const float4 b = *(const float4*)(track_emb + (size_t)s1 * D + l * 4);
  uint2 o;
  o.x = (u32)f32_to_bf16_rn(0.5f * (a.x + b.x)) |
        ((u32)f32_to_bf16_rn(0.5f * (a.y + b.y)) << 16);
  o.y = (u32)f32_to_bf16_rn(0.5f * (a.z + b.z)) |
        ((u32)f32_to_bf16_rn(0.5f * (a.w + b.w)) << 16);
  *(uint2*)(ph + (size_t)p * D + l * 4) = o;
}

// Kernel C: out[e] = dot(ph[src[e]], embh[dst[e]]) over bf16 rows (128 B each).
// 8 lanes per edge, each lane loads uint4 = 8 bf16 of both rows.
__global__ void __launch_bounds__(256) edge_score_bf16_kernel(
    const u16* __restrict__ ph,
    const u16* __restrict__ embh,
    const int* __restrict__ esrc,
    const int* __restrict__ edst,
    float* __restrict__ out,
    int E) {
  long tid = (long)blockIdx.x * blockDim.x + threadIdx.x;
  int e = (int)(tid >> 3);
  int l = (int)(tid & 7);              // 8 lanes x 16 B
  if (e >= E) return;
  int s = esrc[e];
  int d = edst[e];
  const uint4 av = *(const uint4*)(ph   + (size_t)s * D + l * 8);
  const uint4 bv = *(const uint4*)(embh + (size_t)d * D + l * 8);
  float v = 0.f;
  const u32 aw[4] = {av.x, av.y, av.z, av.w};
  const u32 bw[4] = {bv.x, bv.y, bv.z, bv.w};
#pragma unroll
  for (int k = 0; k < 4; ++k) {
    float alo = __uint_as_float(aw[k] << 16);
    float ahi = __uint_as_float(aw[k] & 0xFFFF0000u);
    float blo = __uint_as_float(bw[k] << 16);
    float bhi = __uint_as_float(bw[k] & 0xFFFF0000u);
    v = fmaf(alo, blo, v);
    v = fmaf(ahi, bhi, v);
  }
  v += __shfl_xor(v, 1, 64);
  v += __shfl_xor(v, 2, 64);
  v += __shfl_xor(v, 4, 64);
  if (l == 0) out[e] = v;
}

// ---------------- f32 fallback (ws too small) ----------------

__global__ void __launch_bounds__(256) ph_build_f32_kernel(
    const float* __restrict__ track_emb, const int* __restrict__ sampled,
    float* __restrict__ ph, int P) {
  int tid = blockIdx.x * blockDim.x + threadIdx.x;
  int p = tid >> 4, l = tid & 15;
  if (p >= P) return;
  int s0 = sampled[2 * p + 0], s1 = sampled[2 * p + 1];
  const float4 a = *(const float4*)(track_emb + (size_t)s0 * D + l * 4);
  const float4 b = *(const float4*)(track_emb + (size_t)s1 * D + l * 4);
  float4 r;
  r.x = 0.5f * (a.x + b.x); r.y = 0.5f * (a.y + b.y);
  r.z = 0.5f * (a.z + b.z); r.w = 0.5f * (a.w + b.w);
  *(float4*)(ph + (size_t)p * D + l * 4) = r;
}

__global__ void __launch_bounds__(256) edge_score_f32_kernel(
    const float* __restrict__ ph, const float* __restrict__ track_emb,
    const int* __restrict__ esrc, const int* __restrict__ edst,
    float* __restrict__ out, int E) {
  int tid = blockIdx.x * blockDim.x + threadIdx.x;
  int e = tid >> 4, l = tid & 15;
  if (e >= E) return;
  int s = esrc[e], d = edst[e];
  const float4 a = *(const float4*)(ph + (size_t)s * D + l * 4);
  const float4 b = *(const float4*)(track_emb + (size_t)d * D + l * 4);
  float v = a.x * b.x + a.y * b.y + a.z * b.z + a.w * b.w;
  v += __shfl_xor(v, 1, 64);
  v += __shfl_xor(v, 2, 64);
  v += __shfl_xor(v, 4, 64);
  if (l == 0) out[e] = v;
}

extern "C" void kernel_launch(void* const* d_in, const int* in_sizes, int n_in,
                              void* d_out, int out_size, void* d_ws, size_t ws_size,
                              hipStream_t stream) {
  const float* track_emb = (const float*)d_in[0];   // [T, 64] f32
  const int*   edge_src  = (const int*)d_in[1];     // [E]
  const int*   edge_dst  = (const int*)d_in[2];     // [E]
  const int*   sampled   = (const int*)d_in[3];     // [P, 2]
  float* out = (float*)d_out;                       // [E] f32

  const int E = in_sizes[1];
  const int P = in_sizes[3] / 2;
  const int T = in_sizes[0] / D;

  const size_t embh_bytes = (size_t)T * D * sizeof(u16);   // 64 MB
  const size_t ph_bytes   = (size_t)P * D * sizeof(u16);   // 12.8 MB

  if (ws_size >= embh_bytes + ph_bytes) {
    u16* embh = (u16*)d_ws;
    u16* ph   = (u16*)((char*)d_ws + embh_bytes);

    // A: convert track_emb to bf16 (grid-stride)
    long n4 = (long)T * (D / 4);
    conv_bf16_kernel<<<4096, 256, 0, stream>>>(
        (const float4*)track_emb, (uint2*)embh, n4);

    // B: build ph (bf16)
    {
      long t = (long)P * 16;
      int blocks = (int)((t + 255) / 256);
      ph_build_bf16_kernel<<<blocks, 256, 0, stream>>>(track_emb, sampled, ph, P);
    }

    // C: edge scores
    {
      long t = (long)E * 8;
      int blocks = (int)((t + 255) / 256);
      edge_score_bf16_kernel<<<blocks, 256, 0, stream>>>(ph, embh, edge_src, edge_dst, out, E);
    }
  } else {
    // fallback: f32 path (round-1 kernels)
    float* ph = (float*)d_ws;
    {
      long t = (long)P * 16;
      int blocks = (int)((t + 255) / 256);
      ph_build_f32_kernel<<<blocks, 256, 0, stream>>>(track_emb, sampled, ph, P);
    }
    {
      long t = (long)E * 16;
      int blocks = (int)((t + 255) / 256);
      edge_score_f32_kernel<<<blocks, 256, 0, stream>>>(ph, track_emb, edge_src, edge_dst, out, E);
    }
  }
}